// Round 1
// baseline (1288.018 us; speedup 1.0000x reference)
//
#include <hip/hip_runtime.h>
#include <hip/hip_bf16.h>
#include <cstdint>
#include <cstddef>

// Problem constants: B=128, S=512, D=768, H=12, DH=64
// Attention runs over the BATCH axis: 6144 heads (s,h), seq-len 128, head-dim 64.
// Mask is INVERTED-causal: j<=i (incl diagonal) masked to -10000; row 127 fully
// masked -> uniform 1/128 softmax (reproduced exactly in fp32).

typedef __attribute__((ext_vector_type(8))) short bf16x8_t;  // 8 bf16 (4 VGPRs)
typedef __attribute__((ext_vector_type(4))) float f32x4_t;   // 4 fp32 acc

__device__ inline unsigned short f2bf(float x) {
  union { float f; unsigned int u; } v; v.f = x;
  return (unsigned short)((v.u + 0x7FFFu + ((v.u >> 16) & 1u)) >> 16);  // RNE
}

#define GLL16(gp, lp) __builtin_amdgcn_global_load_lds(                      \
    (const __attribute__((address_space(1))) void*)(gp),                     \
    (__attribute__((address_space(3))) void*)(lp), 16, 0, 0)

// ---------------------------------------------------------------- fp32->bf16
__global__ __launch_bounds__(256) void cvt_kernel(const float* __restrict__ in,
                                                  unsigned short* __restrict__ out,
                                                  int n4) {
  int i = blockIdx.x * 256 + threadIdx.x;
  if (i >= n4) return;
  const float4 v = ((const float4*)in)[i];
  ushort4 o;
  o.x = f2bf(v.x); o.y = f2bf(v.y); o.z = f2bf(v.z); o.w = f2bf(v.w);
  ((ushort4*)out)[i] = o;
}

// b_dense is returned as the 2nd tuple element -> tail of d_out, fp32 copy.
__global__ void bias_tail(const float* __restrict__ b, float* __restrict__ out) {
  int i = blockIdx.x * 256 + threadIdx.x;
  if (i < 768) out[(size_t)128 * 512 * 768 + i] = b[i];
}

// ------------------------------------------------- GEMM1: qkv = X @ Wqkv^T + b
// m97 recipe: 128x128 tile, BK=32, 4 waves in 2x2, 4x4 16x16x32 mfma per wave,
// global_load_lds width=16 staging. Epilogue scatters into Q/K/V [S,H,B,DH] bf16.
__global__ __launch_bounds__(256) void gemm_qkv(
    const unsigned short* __restrict__ A,    // Xb  [65536 x 768] bf16
    const unsigned short* __restrict__ Bt,   // Wqb [2304 x 768] bf16
    const float* __restrict__ bias,          // b_qkv [2304] fp32
    unsigned short* __restrict__ Qb,
    unsigned short* __restrict__ Kb,
    unsigned short* __restrict__ Vb) {
  __shared__ unsigned short As[128 * 32];
  __shared__ unsigned short Bs[128 * 32];
  const int tid = threadIdx.x;
  const int wave = tid >> 6, lane = tid & 63;
  const int lane15 = lane & 15, quad = lane >> 4;
  const int mBase = blockIdx.y * 128;
  const int nBase = blockIdx.x * 128;
  const int wm = (wave >> 1) * 64;
  const int wn = (wave & 1) * 64;

  f32x4_t acc[4][4];
#pragma unroll
  for (int i = 0; i < 4; ++i)
#pragma unroll
    for (int j = 0; j < 4; ++j) { f32x4_t z = {0.f, 0.f, 0.f, 0.f}; acc[i][j] = z; }

  // staging: wave w covers rows [w*32, w*32+32), 2 GLL16 each for A and B.
  const int srow = wave * 32 + (lane >> 2);   // 4 lanes per row
  const int kcol = (lane & 3) * 8;            // 8 bf16 = 16 B per lane
  const unsigned short* Ag = A + (size_t)(mBase + srow) * 768 + kcol;
  const unsigned short* Bg = Bt + (size_t)(nBase + srow) * 768 + kcol;
  unsigned short* lA = &As[(wave * 32) * 32];
  unsigned short* lB = &Bs[(wave * 32) * 32];

  for (int k0 = 0; k0 < 768; k0 += 32) {
    GLL16(Ag + k0, lA);
    GLL16(Ag + 16 * 768 + k0, lA + 16 * 32);
    GLL16(Bg + k0, lB);
    GLL16(Bg + 16 * 768 + k0, lB + 16 * 32);
    __syncthreads();  // drains vmcnt(0): staged tiles visible
    bf16x8_t aF[4], bF[4];
#pragma unroll
    for (int im = 0; im < 4; ++im)
      aF[im] = *(const bf16x8_t*)&As[(wm + im * 16 + lane15) * 32 + quad * 8];
#pragma unroll
    for (int in = 0; in < 4; ++in)
      bF[in] = *(const bf16x8_t*)&Bs[(wn + in * 16 + lane15) * 32 + quad * 8];
#pragma unroll
    for (int im = 0; im < 4; ++im)
#pragma unroll
      for (int in = 0; in < 4; ++in)
        acc[im][in] = __builtin_amdgcn_mfma_f32_16x16x32_bf16(aF[im], bF[in], acc[im][in], 0, 0, 0);
    __syncthreads();  // all waves done reading before next stage
  }

  // Epilogue: C/D layout col=lane&15 (e), row=quad*4+reg (m). e = h*192 + c;
  // c/64 selects q/k/v; 16-wide tiles never straddle a 64-wide section.
#pragma unroll
  for (int in = 0; in < 4; ++in) {
    const int e = nBase + wn + in * 16 + lane15;
    const float bv = bias[e];
    const int h = e / 192;
    const int c = e - h * 192;
    const int sec = c >> 6;
    const int dh = c & 63;
    unsigned short* dst = (sec == 0) ? Qb : ((sec == 1) ? Kb : Vb);
#pragma unroll
    for (int im = 0; im < 4; ++im) {
#pragma unroll
      for (int r = 0; r < 4; ++r) {
        const int m = mBase + wm + im * 16 + quad * 4 + r;
        const int bb = m >> 9;        // batch
        const int ss = m & 511;       // seq
        dst[(size_t)((ss * 12 + h) * 128 + bb) * 64 + dh] = f2bf(acc[im][in][r] + bv);
      }
    }
  }
}

// ------------------------------------------------------- attention, 1 block/head
// Q/K/V tiles are 128x64 bf16. Scores 128x128 in fp32 regs; softmax per row
// across the 16 lanes of a quad (shfl_xor width 16); P round-trips through LDS
// (C-layout -> A-operand layout); V staged transposed for contiguous B-frags.
__global__ __launch_bounds__(256) void attn_kernel(
    const unsigned short* __restrict__ Qg,
    const unsigned short* __restrict__ Kg,
    const unsigned short* __restrict__ Vg,
    unsigned short* __restrict__ Ctx) {       // [B,S,D] bf16
  __shared__ unsigned short Qs[128 * 64];
  __shared__ unsigned short Ks[128 * 64];
  __shared__ unsigned short Vt[64 * 128];     // Vt[dh][c]
  __shared__ unsigned short Ps[4][16 * 128];  // per-wave P chunk (16 rows)

  const int n = blockIdx.x;         // head = s*12 + h
  const int s = n / 12;
  const int h = n - s * 12;
  const int tid = threadIdx.x;
  const int wave = tid >> 6, lane = tid & 63;
  const int lane15 = lane & 15, quad = lane >> 4;
  const size_t base = (size_t)n * 8192;

  {
    const uint4* q4 = (const uint4*)(Qg + base);
    const uint4* k4 = (const uint4*)(Kg + base);
    uint4* qs4 = (uint4*)Qs;
    uint4* ks4 = (uint4*)Ks;
#pragma unroll
    for (int i = 0; i < 4; ++i) {
      qs4[tid + i * 256] = q4[tid + i * 256];
      ks4[tid + i * 256] = k4[tid + i * 256];
    }
    const unsigned short* vg = Vg + base;
#pragma unroll
    for (int ii = 0; ii < 32; ++ii) {
      int i = tid + ii * 256;
      int c = i >> 6, dh = i & 63;
      Vt[dh * 128 + c] = vg[i];     // transpose on the way in
    }
  }
  __syncthreads();

  // QK^T: wave w computes score rows [w*32, w*32+32) x all 128 cols.
  f32x4_t sc[2][8];
#pragma unroll
  for (int im = 0; im < 2; ++im)
#pragma unroll
    for (int in = 0; in < 8; ++in) { f32x4_t z = {0.f, 0.f, 0.f, 0.f}; sc[im][in] = z; }

#pragma unroll
  for (int kk = 0; kk < 2; ++kk) {
    bf16x8_t a0 = *(const bf16x8_t*)&Qs[(wave * 32 + lane15) * 64 + kk * 32 + quad * 8];
    bf16x8_t a1 = *(const bf16x8_t*)&Qs[(wave * 32 + 16 + lane15) * 64 + kk * 32 + quad * 8];
#pragma unroll
    for (int in = 0; in < 8; ++in) {
      bf16x8_t b = *(const bf16x8_t*)&Ks[(in * 16 + lane15) * 64 + kk * 32 + quad * 8];
      sc[0][in] = __builtin_amdgcn_mfma_f32_16x16x32_bf16(a0, b, sc[0][in], 0, 0, 0);
      sc[1][in] = __builtin_amdgcn_mfma_f32_16x16x32_bf16(a1, b, sc[1][in], 0, 0, 0);
    }
  }

  unsigned short* myP = &Ps[wave][0];

#pragma unroll 1
  for (int im = 0; im < 2; ++im) {
    // softmax on this wave's 16-row chunk (rows wave*32 + im*16 + quad*4 + r)
#pragma unroll
    for (int r = 0; r < 4; ++r) {
      const int row = wave * 32 + im * 16 + quad * 4 + r;
      float vals[8];
      float mx = -3.0e38f;
#pragma unroll
      for (int in = 0; in < 8; ++in) {
        const int col = in * 16 + lane15;
        float v = sc[im][in][r] * 0.125f;          // /sqrt(64)
        v = (col <= row) ? -10000.0f : v;          // inverted-causal mask
        vals[in] = v;
        mx = fmaxf(mx, v);
      }
      mx = fmaxf(mx, __shfl_xor(mx, 1, 16));
      mx = fmaxf(mx, __shfl_xor(mx, 2, 16));
      mx = fmaxf(mx, __shfl_xor(mx, 4, 16));
      mx = fmaxf(mx, __shfl_xor(mx, 8, 16));
      float sum = 0.f;
#pragma unroll
      for (int in = 0; in < 8; ++in) {
        const float e_ = __expf(vals[in] - mx);
        vals[in] = e_;
        sum += e_;
      }
      sum += __shfl_xor(sum, 1, 16);
      sum += __shfl_xor(sum, 2, 16);
      sum += __shfl_xor(sum, 4, 16);
      sum += __shfl_xor(sum, 8, 16);
      const float inv = 1.0f / sum;   // row 127: all -1e4 -> uniform 1/128, exact
#pragma unroll
      for (int in = 0; in < 8; ++in)
        myP[(quad * 4 + r) * 128 + in * 16 + lane15] = f2bf(vals[in] * inv);
    }
    __syncthreads();  // conservative: ensure P writes land before ds_read_b128

    // P·V: 16 rows x 64 cols, K=128
    f32x4_t oc[4];
#pragma unroll
    for (int nt = 0; nt < 4; ++nt) { f32x4_t z = {0.f, 0.f, 0.f, 0.f}; oc[nt] = z; }
#pragma unroll
    for (int kk = 0; kk < 4; ++kk) {
      bf16x8_t a = *(const bf16x8_t*)&myP[lane15 * 128 + kk * 32 + quad * 8];
#pragma unroll
      for (int nt = 0; nt < 4; ++nt) {
        bf16x8_t b = *(const bf16x8_t*)&Vt[(nt * 16 + lane15) * 128 + kk * 32 + quad * 8];
        oc[nt] = __builtin_amdgcn_mfma_f32_16x16x32_bf16(a, b, oc[nt], 0, 0, 0);
      }
    }
    // ctx[b, s, h*64+dh]; rows of this tile are batch indices
#pragma unroll
    for (int nt = 0; nt < 4; ++nt) {
#pragma unroll
      for (int r = 0; r < 4; ++r) {
        const int bb = wave * 32 + im * 16 + quad * 4 + r;
        Ctx[((size_t)bb * 512 + s) * 768 + h * 64 + nt * 16 + lane15] = f2bf(oc[nt][r]);
      }
    }
    __syncthreads();
  }
}

// ------------------------------------------------- GEMM2: out = ctx @ Wdense^T
__global__ __launch_bounds__(256) void gemm_out(
    const unsigned short* __restrict__ A,    // ctx bf16 [65536 x 768]
    const unsigned short* __restrict__ Bt,   // Wdb bf16 [768 x 768]
    float* __restrict__ Out) {               // fp32 [65536 x 768]
  __shared__ unsigned short As[128 * 32];
  __shared__ unsigned short Bs[128 * 32];
  const int tid = threadIdx.x;
  const int wave = tid >> 6, lane = tid & 63;
  const int lane15 = lane & 15, quad = lane >> 4;
  const int mBase = blockIdx.y * 128;
  const int nBase = blockIdx.x * 128;
  const int wm = (wave >> 1) * 64;
  const int wn = (wave & 1) * 64;

  f32x4_t acc[4][4];
#pragma unroll
  for (int i = 0; i < 4; ++i)
#pragma unroll
    for (int j = 0; j < 4; ++j) { f32x4_t z = {0.f, 0.f, 0.f, 0.f}; acc[i][j] = z; }

  const int srow = wave * 32 + (lane >> 2);
  const int kcol = (lane & 3) * 8;
  const unsigned short* Ag = A + (size_t)(mBase + srow) * 768 + kcol;
  const unsigned short* Bg = Bt + (size_t)(nBase + srow) * 768 + kcol;
  unsigned short* lA = &As[(wave * 32) * 32];
  unsigned short* lB = &Bs[(wave * 32) * 32];

  for (int k0 = 0; k0 < 768; k0 += 32) {
    GLL16(Ag + k0, lA);
    GLL16(Ag + 16 * 768 + k0, lA + 16 * 32);
    GLL16(Bg + k0, lB);
    GLL16(Bg + 16 * 768 + k0, lB + 16 * 32);
    __syncthreads();
    bf16x8_t aF[4], bF[4];
#pragma unroll
    for (int im = 0; im < 4; ++im)
      aF[im] = *(const bf16x8_t*)&As[(wm + im * 16 + lane15) * 32 + quad * 8];
#pragma unroll
    for (int in = 0; in < 4; ++in)
      bF[in] = *(const bf16x8_t*)&Bs[(wn + in * 16 + lane15) * 32 + quad * 8];
#pragma unroll
    for (int im = 0; im < 4; ++im)
#pragma unroll
      for (int in = 0; in < 4; ++in)
        acc[im][in] = __builtin_amdgcn_mfma_f32_16x16x32_bf16(aF[im], bF[in], acc[im][in], 0, 0, 0);
    __syncthreads();
  }

#pragma unroll
  for (int in = 0; in < 4; ++in) {
    const int e = nBase + wn + in * 16 + lane15;
#pragma unroll
    for (int im = 0; im < 4; ++im)
#pragma unroll
      for (int r = 0; r < 4; ++r) {
        const int m = mBase + wm + im * 16 + quad * 4 + r;
        Out[(size_t)m * 768 + e] = acc[im][in][r];
      }
  }
}

// ---------------------------------------------------------------------- launch
extern "C" void kernel_launch(void* const* d_in, const int* in_sizes, int n_in,
                              void* d_out, int out_size, void* d_ws, size_t ws_size,
                              hipStream_t stream) {
  const float* X    = (const float*)d_in[0];   // [128,512,768]
  const float* Wqkv = (const float*)d_in[1];   // [2304,768]
  const float* bqkv = (const float*)d_in[2];   // [2304]
  const float* Wd   = (const float*)d_in[3];   // [768,768]
  const float* bd   = (const float*)d_in[4];   // [768]
  float* out = (float*)d_out;

  // ws layout (bytes); ctx reuses the Xb region after gemm_qkv.
  char* ws = (char*)d_ws;
  unsigned short* Xb  = (unsigned short*)(ws);                // 100,663,296 B (later: ctx)
  unsigned short* Qb  = (unsigned short*)(ws + 100663296);    // [S,H,B,DH] bf16
  unsigned short* Kb  = (unsigned short*)(ws + 201326592);
  unsigned short* Vb  = (unsigned short*)(ws + 301989888);
  unsigned short* Wqb = (unsigned short*)(ws + 402653184);    // 3,538,944 B
  unsigned short* Wdb = (unsigned short*)(ws + 406192128);    // 1,179,648 B

  cvt_kernel<<<dim3(49152), 256, 0, stream>>>(X, Xb, 12582912);
  cvt_kernel<<<dim3(1728), 256, 0, stream>>>(Wqkv, Wqb, 442368);
  cvt_kernel<<<dim3(576), 256, 0, stream>>>(Wd, Wdb, 147456);
  bias_tail<<<dim3(3), 256, 0, stream>>>(bd, out);

  gemm_qkv<<<dim3(18, 512), 256, 0, stream>>>(Xb, Wqb, bqkv, Qb, Kb, Vb);
  attn_kernel<<<dim3(6144), 256, 0, stream>>>(Qb, Kb, Vb, Xb /* ctx reuse */);
  gemm_out<<<dim3(6, 512), 256, 0, stream>>>(Xb, Wdb, out);
}

// Round 2
// 1260.093 us; speedup vs baseline: 1.0222x; 1.0222x over previous
//
#include <hip/hip_runtime.h>
#include <hip/hip_bf16.h>
#include <cstdint>
#include <cstddef>

// B=128, S=512, D=768, H=12, DH=64. Attention over BATCH axis: 6144 heads
// (s,h), seq-len 128, head-dim 64. Mask is inverted-causal (j<=i masked).
// Row 127 fully masked -> uniform 1/128 (exact in fp32).
//
// R2 changes vs R1:
//  - chunk-major LDS subtiles in GEMMs: frag ds_read_b128 = base + lane*16B,
//    contiguous 1024B/wave -> zero bank conflicts (was ~8-way).
//  - gemm_qkv writes natural [65536 x 2304] bf16 (L2 merges 128B row chunks);
//    head gather moved to attn load (128B contiguous segments).
//  - attn LDS padded to stride==4 mod 32 dwords (72/136 elem): uniform banks.

typedef __attribute__((ext_vector_type(8))) short bf16x8_t;
typedef __attribute__((ext_vector_type(4))) float f32x4_t;

__device__ inline unsigned short f2bf(float x) {
  union { float f; unsigned int u; } v; v.f = x;
  return (unsigned short)((v.u + 0x7FFFu + ((v.u >> 16) & 1u)) >> 16);  // RNE
}

#define GLL16(gp, lp) __builtin_amdgcn_global_load_lds(                      \
    (const __attribute__((address_space(1))) void*)(gp),                     \
    (__attribute__((address_space(3))) void*)(lp), 16, 0, 0)

// ---------------------------------------------------------------- fp32->bf16
__global__ __launch_bounds__(256) void cvt_kernel(const float* __restrict__ in,
                                                  unsigned short* __restrict__ out,
                                                  int n4) {
  int i = blockIdx.x * 256 + threadIdx.x;
  if (i >= n4) return;
  const float4 v = ((const float4*)in)[i];
  ushort4 o;
  o.x = f2bf(v.x); o.y = f2bf(v.y); o.z = f2bf(v.z); o.w = f2bf(v.w);
  ((ushort4*)out)[i] = o;
}

__global__ void bias_tail(const float* __restrict__ b, float* __restrict__ out) {
  int i = blockIdx.x * 256 + threadIdx.x;
  if (i < 768) out[(size_t)128 * 512 * 768 + i] = b[i];
}

// ------------------------------------------------- GEMM1: qkv = X @ Wqkv^T + b
// 128x128 tile, BK=32, 2x2 waves, 4x4 mfma_16x16x32. Chunk-major LDS subtiles:
// one GLL16 stages a 16x32 subtile with lane l -> (row=l&15, chunk=l>>4), so
// frag reads are subtile_base + lane*16B (conflict-free).
__global__ __launch_bounds__(256) void gemm_qkv(
    const unsigned short* __restrict__ A,    // Xb  [65536 x 768] bf16
    const unsigned short* __restrict__ Bt,   // Wqb [2304 x 768] bf16
    const float* __restrict__ bias,          // b_qkv [2304] fp32
    unsigned short* __restrict__ QKV) {      // [65536 x 2304] bf16
  __shared__ unsigned short As[128 * 32];
  __shared__ unsigned short Bs[128 * 32];
  const int tid = threadIdx.x;
  const int wave = tid >> 6, lane = tid & 63;
  const int lane15 = lane & 15, quad = lane >> 4;
  const int mBase = blockIdx.y * 128;
  const int nBase = blockIdx.x * 128;
  const int wm = (wave >> 1) * 64;
  const int wn = (wave & 1) * 64;

  f32x4_t acc[4][4];
#pragma unroll
  for (int i = 0; i < 4; ++i)
#pragma unroll
    for (int j = 0; j < 4; ++j) { f32x4_t z = {0.f, 0.f, 0.f, 0.f}; acc[i][j] = z; }

  // staging: lane l covers (row = l&15, kchunk = l>>4) of a 16x32 subtile
  const int r16 = lane & 15;
  const int ck8 = (lane >> 4) * 8;
  const unsigned short* Ag = A + (size_t)(mBase + wave * 32 + r16) * 768 + ck8;
  const unsigned short* Bg = Bt + (size_t)(nBase + wave * 32 + r16) * 768 + ck8;
  unsigned short* lA = &As[wave * 1024];   // 2 subtiles of 512 elem per wave
  unsigned short* lB = &Bs[wave * 1024];

  const int aOff = ((wave >> 1) * 4) * 512 + lane * 8;  // wm/16 subtiles
  const int bOff = ((wave & 1) * 4) * 512 + lane * 8;

  for (int k0 = 0; k0 < 768; k0 += 32) {
    GLL16(Ag + k0, lA);
    GLL16(Ag + 16 * 768 + k0, lA + 512);
    GLL16(Bg + k0, lB);
    GLL16(Bg + 16 * 768 + k0, lB + 512);
    __syncthreads();
    bf16x8_t aF[4], bF[4];
#pragma unroll
    for (int im = 0; im < 4; ++im) aF[im] = *(const bf16x8_t*)&As[aOff + im * 512];
#pragma unroll
    for (int in = 0; in < 4; ++in) bF[in] = *(const bf16x8_t*)&Bs[bOff + in * 512];
#pragma unroll
    for (int im = 0; im < 4; ++im)
#pragma unroll
      for (int in = 0; in < 4; ++in)
        acc[im][in] = __builtin_amdgcn_mfma_f32_16x16x32_bf16(aF[im], bF[in], acc[im][in], 0, 0, 0);
    __syncthreads();
  }

  float bv[4];
#pragma unroll
  for (int in = 0; in < 4; ++in) bv[in] = bias[nBase + wn + in * 16 + lane15];

  // C/D: col=lane15, row=quad*4+r. Natural [m][e]; 4 in-chunks of 32B cover a
  // contiguous 128B row window -> L2 merges to full lines.
#pragma unroll
  for (int im = 0; im < 4; ++im) {
#pragma unroll
    for (int r = 0; r < 4; ++r) {
      const int m = mBase + wm + im * 16 + quad * 4 + r;
      unsigned short* orow = QKV + (size_t)m * 2304 + nBase + wn + lane15;
#pragma unroll
      for (int in = 0; in < 4; ++in)
        orow[in * 16] = f2bf(acc[im][in][r] + bv[in]);
    }
  }
}

// ------------------------------------------------------- attention, 1 block/head
__global__ __launch_bounds__(256) void attn_kernel(
    const unsigned short* __restrict__ QKV,   // [65536 x 2304] bf16
    unsigned short* __restrict__ Ctx) {       // [B,S,D] bf16
  __shared__ unsigned short Qs[128 * 72];     // row stride 72 (144B, ==4 mod 32 dw)
  __shared__ unsigned short Ks[128 * 72];
  __shared__ unsigned short Vt[64 * 136];     // Vt[dh][c], stride 136 (272B)
  __shared__ unsigned short Ps[4][16 * 136];  // per-wave P chunk

  const int n = blockIdx.x;         // head = s*12 + h
  const int s = n / 12;
  const int h = n - s * 12;
  const int tid = threadIdx.x;
  const int wave = tid >> 6, lane = tid & 63;
  const int lane15 = lane & 15, quad = lane >> 4;

  // ---- stage Q,K: per (s,h) each of 128 batch rows is 128B contiguous
#pragma unroll
  for (int it = 0; it < 4; ++it) {
    const int idx = it * 256 + tid;
    const int bb = idx >> 3, seg = idx & 7;
    const size_t g = (size_t)(bb * 512 + s) * 2304 + h * 192 + seg * 8;
    *(uint4*)&Qs[bb * 72 + seg * 8] = *(const uint4*)&QKV[g];
    *(uint4*)&Ks[bb * 72 + seg * 8] = *(const uint4*)&QKV[g + 64];
  }
  // ---- stage V transposed: coalesced uint4 row loads, scalar LDS writes
  {
    const int c = tid & 127, half = tid >> 7;
    const size_t vb = (size_t)(c * 512 + s) * 2304 + h * 192 + 128;
#pragma unroll
    for (int dd = 0; dd < 4; ++dd) {
      const int dseg = half * 4 + dd;
      uint4 v = *(const uint4*)&QKV[vb + dseg * 8];
      const unsigned short* pv = (const unsigned short*)&v;
#pragma unroll
      for (int j = 0; j < 8; ++j) Vt[(dseg * 8 + j) * 136 + c] = pv[j];
    }
  }
  __syncthreads();

  // ---- QK^T: wave w -> score rows [w*32, w*32+32) x 128 cols
  f32x4_t sc[2][8];
#pragma unroll
  for (int im = 0; im < 2; ++im)
#pragma unroll
    for (int in = 0; in < 8; ++in) { f32x4_t z = {0.f, 0.f, 0.f, 0.f}; sc[im][in] = z; }

#pragma unroll
  for (int kk = 0; kk < 2; ++kk) {
    bf16x8_t a0 = *(const bf16x8_t*)&Qs[(wave * 32 + lane15) * 72 + kk * 32 + quad * 8];
    bf16x8_t a1 = *(const bf16x8_t*)&Qs[(wave * 32 + 16 + lane15) * 72 + kk * 32 + quad * 8];
#pragma unroll
    for (int in = 0; in < 8; ++in) {
      bf16x8_t b = *(const bf16x8_t*)&Ks[(in * 16 + lane15) * 72 + kk * 32 + quad * 8];
      sc[0][in] = __builtin_amdgcn_mfma_f32_16x16x32_bf16(a0, b, sc[0][in], 0, 0, 0);
      sc[1][in] = __builtin_amdgcn_mfma_f32_16x16x32_bf16(a1, b, sc[1][in], 0, 0, 0);
    }
  }

  unsigned short* myP = &Ps[wave][0];

#pragma unroll 1
  for (int im = 0; im < 2; ++im) {
#pragma unroll
    for (int r = 0; r < 4; ++r) {
      const int row = wave * 32 + im * 16 + quad * 4 + r;
      float vals[8];
      float mx = -3.0e38f;
#pragma unroll
      for (int in = 0; in < 8; ++in) {
        const int col = in * 16 + lane15;
        float v = sc[im][in][r] * 0.125f;          // /sqrt(64)
        v = (col <= row) ? -10000.0f : v;          // inverted-causal mask
        vals[in] = v;
        mx = fmaxf(mx, v);
      }
      mx = fmaxf(mx, __shfl_xor(mx, 1, 16));
      mx = fmaxf(mx, __shfl_xor(mx, 2, 16));
      mx = fmaxf(mx, __shfl_xor(mx, 4, 16));
      mx = fmaxf(mx, __shfl_xor(mx, 8, 16));
      float sum = 0.f;
#pragma unroll
      for (int in = 0; in < 8; ++in) {
        const float e_ = __expf(vals[in] - mx);
        vals[in] = e_;
        sum += e_;
      }
      sum += __shfl_xor(sum, 1, 16);
      sum += __shfl_xor(sum, 2, 16);
      sum += __shfl_xor(sum, 4, 16);
      sum += __shfl_xor(sum, 8, 16);
      const float inv = 1.0f / sum;   // row 127: uniform 1/128, exact
#pragma unroll
      for (int in = 0; in < 8; ++in)
        myP[(quad * 4 + r) * 136 + in * 16 + lane15] = f2bf(vals[in] * inv);
    }
    __syncthreads();

    // P·V: 16 rows x 64 cols, K=128
    f32x4_t oc[4];
#pragma unroll
    for (int nt = 0; nt < 4; ++nt) { f32x4_t z = {0.f, 0.f, 0.f, 0.f}; oc[nt] = z; }
#pragma unroll
    for (int kk = 0; kk < 4; ++kk) {
      bf16x8_t a = *(const bf16x8_t*)&myP[lane15 * 136 + kk * 32 + quad * 8];
#pragma unroll
      for (int nt = 0; nt < 4; ++nt) {
        bf16x8_t b = *(const bf16x8_t*)&Vt[(nt * 16 + lane15) * 136 + kk * 32 + quad * 8];
        oc[nt] = __builtin_amdgcn_mfma_f32_16x16x32_bf16(a, b, oc[nt], 0, 0, 0);
      }
    }
#pragma unroll
    for (int nt = 0; nt < 4; ++nt) {
#pragma unroll
      for (int r = 0; r < 4; ++r) {
        const int bb = wave * 32 + im * 16 + quad * 4 + r;
        Ctx[((size_t)bb * 512 + s) * 768 + h * 64 + nt * 16 + lane15] = f2bf(oc[nt][r]);
      }
    }
    __syncthreads();
  }
}

// ------------------------------------------------- GEMM2: out = ctx @ Wdense^T
__global__ __launch_bounds__(256) void gemm_out(
    const unsigned short* __restrict__ A,    // ctx bf16 [65536 x 768]
    const unsigned short* __restrict__ Bt,   // Wdb bf16 [768 x 768]
    float* __restrict__ Out) {               // fp32 [65536 x 768]
  __shared__ unsigned short As[128 * 32];
  __shared__ unsigned short Bs[128 * 32];
  const int tid = threadIdx.x;
  const int wave = tid >> 6, lane = tid & 63;
  const int lane15 = lane & 15, quad = lane >> 4;
  const int mBase = blockIdx.y * 128;
  const int nBase = blockIdx.x * 128;
  const int wm = (wave >> 1) * 64;
  const int wn = (wave & 1) * 64;

  f32x4_t acc[4][4];
#pragma unroll
  for (int i = 0; i < 4; ++i)
#pragma unroll
    for (int j = 0; j < 4; ++j) { f32x4_t z = {0.f, 0.f, 0.f, 0.f}; acc[i][j] = z; }

  const int r16 = lane & 15;
  const int ck8 = (lane >> 4) * 8;
  const unsigned short* Ag = A + (size_t)(mBase + wave * 32 + r16) * 768 + ck8;
  const unsigned short* Bg = Bt + (size_t)(nBase + wave * 32 + r16) * 768 + ck8;
  unsigned short* lA = &As[wave * 1024];
  unsigned short* lB = &Bs[wave * 1024];

  const int aOff = ((wave >> 1) * 4) * 512 + lane * 8;
  const int bOff = ((wave & 1) * 4) * 512 + lane * 8;

  for (int k0 = 0; k0 < 768; k0 += 32) {
    GLL16(Ag + k0, lA);
    GLL16(Ag + 16 * 768 + k0, lA + 512);
    GLL16(Bg + k0, lB);
    GLL16(Bg + 16 * 768 + k0, lB + 512);
    __syncthreads();
    bf16x8_t aF[4], bF[4];
#pragma unroll
    for (int im = 0; im < 4; ++im) aF[im] = *(const bf16x8_t*)&As[aOff + im * 512];
#pragma unroll
    for (int in = 0; in < 4; ++in) bF[in] = *(const bf16x8_t*)&Bs[bOff + in * 512];
#pragma unroll
    for (int im = 0; im < 4; ++im)
#pragma unroll
      for (int in = 0; in < 4; ++in)
        acc[im][in] = __builtin_amdgcn_mfma_f32_16x16x32_bf16(aF[im], bF[in], acc[im][in], 0, 0, 0);
    __syncthreads();
  }

#pragma unroll
  for (int im = 0; im < 4; ++im) {
#pragma unroll
    for (int r = 0; r < 4; ++r) {
      const int m = mBase + wm + im * 16 + quad * 4 + r;
      float* orow = Out + (size_t)m * 768 + nBase + wn + lane15;
#pragma unroll
      for (int in = 0; in < 4; ++in)
        orow[in * 16] = acc[im][in][r];
    }
  }
}

// ---------------------------------------------------------------------- launch
extern "C" void kernel_launch(void* const* d_in, const int* in_sizes, int n_in,
                              void* d_out, int out_size, void* d_ws, size_t ws_size,
                              hipStream_t stream) {
  const float* X    = (const float*)d_in[0];   // [128,512,768]
  const float* Wqkv = (const float*)d_in[1];   // [2304,768]
  const float* bqkv = (const float*)d_in[2];   // [2304]
  const float* Wd   = (const float*)d_in[3];   // [768,768]
  const float* bd   = (const float*)d_in[4];   // [768]
  float* out = (float*)d_out;

  char* ws = (char*)d_ws;
  unsigned short* Xb  = (unsigned short*)(ws);                // 100,663,296 B (later: ctx)
  unsigned short* QKV = (unsigned short*)(ws + 100663296);    // [65536,2304] bf16, 301,989,888 B
  unsigned short* Wqb = (unsigned short*)(ws + 402653184);    // 3,538,944 B
  unsigned short* Wdb = (unsigned short*)(ws + 406192128);    // 1,179,648 B

  cvt_kernel<<<dim3(49152), 256, 0, stream>>>(X, Xb, 12582912);
  cvt_kernel<<<dim3(1728), 256, 0, stream>>>(Wqkv, Wqb, 442368);
  cvt_kernel<<<dim3(576), 256, 0, stream>>>(Wd, Wdb, 147456);
  bias_tail<<<dim3(3), 256, 0, stream>>>(bd, out);

  gemm_qkv<<<dim3(18, 512), 256, 0, stream>>>(Xb, Wqb, bqkv, QKV);
  attn_kernel<<<dim3(6144), 256, 0, stream>>>(QKV, Xb /* ctx reuse */);
  gemm_out<<<dim3(6, 512), 256, 0, stream>>>(Xb, Wdb, out);
}

// Round 3
// 1257.041 us; speedup vs baseline: 1.0246x; 1.0024x over previous
//
#include <hip/hip_runtime.h>
#include <hip/hip_bf16.h>
#include <cstdint>
#include <cstddef>

// B=128, S=512, D=768, H=12, DH=64. Attention over BATCH axis: 6144 heads
// (s,h), seq-len 128, head-dim 64. Mask is inverted-causal (j<=i masked).
//
// R3 changes vs R2 (R2 post-mortem: conflicts->0 / writes->ideal changed
// NOTHING -> kernel is barrier-drain latency-bound, not LDS/write-bound):
//  - GEMMs: BK=64 (12 iters, half the vmcnt(0)+barrier drains; 32 MFMA/barrier)
//  - GEMMs: grid x=m fastest (B-tile stays hot in each XCD L2; A streams via L3)
//  - attn: V staged into Ks region after QK^T, P into Qs region -> 36 KB LDS,
//    4 blocks/CU instead of 2.

typedef __attribute__((ext_vector_type(8))) short bf16x8_t;
typedef __attribute__((ext_vector_type(4))) float f32x4_t;

__device__ inline unsigned short f2bf(float x) {
  union { float f; unsigned int u; } v; v.f = x;
  return (unsigned short)((v.u + 0x7FFFu + ((v.u >> 16) & 1u)) >> 16);  // RNE
}

#define GLL16(gp, lp) __builtin_amdgcn_global_load_lds(                      \
    (const __attribute__((address_space(1))) void*)(gp),                     \
    (__attribute__((address_space(3))) void*)(lp), 16, 0, 0)

// ---------------------------------------------------------------- fp32->bf16
__global__ __launch_bounds__(256) void cvt_kernel(const float* __restrict__ in,
                                                  unsigned short* __restrict__ out,
                                                  int n4) {
  int i = blockIdx.x * 256 + threadIdx.x;
  if (i >= n4) return;
  const float4 v = ((const float4*)in)[i];
  ushort4 o;
  o.x = f2bf(v.x); o.y = f2bf(v.y); o.z = f2bf(v.z); o.w = f2bf(v.w);
  ((ushort4*)out)[i] = o;
}

__global__ void bias_tail(const float* __restrict__ b, float* __restrict__ out) {
  int i = blockIdx.x * 256 + threadIdx.x;
  if (i < 768) out[(size_t)128 * 512 * 768 + i] = b[i];
}

// ------------------------------------------------- GEMM1: qkv = X @ Wqkv^T + b
// 128x128 tile, BK=64, 2x2 waves, per iter: 8 GLL16/wave + 32 MFMA/wave.
// LDS = 16 subtiles of 512 elem; subtile = rowgroup*2 + khalf; lane l of one
// GLL16 holds (row=l&15, chunk=l>>4) -> frag read = subtile*512 + lane*8
// (conflict-free, measured 0 in R2).
__global__ __launch_bounds__(256) void gemm_qkv(
    const unsigned short* __restrict__ A,    // Xb  [65536 x 768] bf16
    const unsigned short* __restrict__ Bt,   // Wqb [2304 x 768] bf16
    const float* __restrict__ bias,          // b_qkv [2304] fp32
    unsigned short* __restrict__ QKV) {      // [65536 x 2304] bf16
  __shared__ unsigned short As[128 * 64];
  __shared__ unsigned short Bs[128 * 64];
  const int tid = threadIdx.x;
  const int wave = tid >> 6, lane = tid & 63;
  const int lane15 = lane & 15, quad = lane >> 4;
  const int mBase = blockIdx.x * 128;   // x = m fastest: A streams, B-tile hot
  const int nBase = blockIdx.y * 128;
  const int wm = (wave >> 1) * 64;
  const int wn = (wave & 1) * 64;

  f32x4_t acc[4][4];
#pragma unroll
  for (int i = 0; i < 4; ++i)
#pragma unroll
    for (int j = 0; j < 4; ++j) { f32x4_t z = {0.f, 0.f, 0.f, 0.f}; acc[i][j] = z; }

  const int r16 = lane & 15;
  const int ck8 = (lane >> 4) * 8;
  const unsigned short* Ag = A + (size_t)(mBase + wave * 32 + r16) * 768 + ck8;
  const unsigned short* Bg = Bt + (size_t)(nBase + wave * 32 + r16) * 768 + ck8;
  unsigned short* lA = &As[wave * 4 * 512];   // wave stages subtiles 4w..4w+3
  unsigned short* lB = &Bs[wave * 4 * 512];

  const int aSub = (wm >> 4) * 2;   // subtile = (aSub + im*2 + kh)
  const int bSub = (wn >> 4) * 2;

  for (int k0 = 0; k0 < 768; k0 += 64) {
    GLL16(Ag + k0, lA);
    GLL16(Ag + k0 + 32, lA + 512);
    GLL16(Ag + 16 * 768 + k0, lA + 1024);
    GLL16(Ag + 16 * 768 + k0 + 32, lA + 1536);
    GLL16(Bg + k0, lB);
    GLL16(Bg + k0 + 32, lB + 512);
    GLL16(Bg + 16 * 768 + k0, lB + 1024);
    GLL16(Bg + 16 * 768 + k0 + 32, lB + 1536);
    __syncthreads();
#pragma unroll
    for (int kh = 0; kh < 2; ++kh) {
      bf16x8_t aF[4], bF[4];
#pragma unroll
      for (int im = 0; im < 4; ++im)
        aF[im] = *(const bf16x8_t*)&As[(aSub + im * 2 + kh) * 512 + lane * 8];
#pragma unroll
      for (int in = 0; in < 4; ++in)
        bF[in] = *(const bf16x8_t*)&Bs[(bSub + in * 2 + kh) * 512 + lane * 8];
#pragma unroll
      for (int im = 0; im < 4; ++im)
#pragma unroll
        for (int in = 0; in < 4; ++in)
          acc[im][in] = __builtin_amdgcn_mfma_f32_16x16x32_bf16(aF[im], bF[in], acc[im][in], 0, 0, 0);
    }
    __syncthreads();
  }

  float bv[4];
#pragma unroll
  for (int in = 0; in < 4; ++in) bv[in] = bias[nBase + wn + in * 16 + lane15];

#pragma unroll
  for (int im = 0; im < 4; ++im) {
#pragma unroll
    for (int r = 0; r < 4; ++r) {
      const int m = mBase + wm + im * 16 + quad * 4 + r;
      unsigned short* orow = QKV + (size_t)m * 2304 + nBase + wn + lane15;
#pragma unroll
      for (int in = 0; in < 4; ++in)
        orow[in * 16] = f2bf(acc[im][in][r] + bv[in]);
    }
  }
}

// ------------------------------------------------------- attention, 1 block/head
// LDS aliasing: V -> Ks region, P -> Qs region (both dead after QK^T phase).
__global__ __launch_bounds__(256) void attn_kernel(
    const unsigned short* __restrict__ QKV,   // [65536 x 2304] bf16
    unsigned short* __restrict__ Ctx) {       // [B,S,D] bf16
  __shared__ unsigned short Qs[128 * 72];     // 9216 elem; later Ps (needs 8704)
  __shared__ unsigned short Ks[128 * 72];     // 9216 elem; later Vt (needs 8704)

  const int n = blockIdx.x;         // head = s*12 + h
  const int s = n / 12;
  const int h = n - s * 12;
  const int tid = threadIdx.x;
  const int wave = tid >> 6, lane = tid & 63;
  const int lane15 = lane & 15, quad = lane >> 4;

  // ---- stage Q,K (128B contiguous per batch row)
#pragma unroll
  for (int it = 0; it < 4; ++it) {
    const int idx = it * 256 + tid;
    const int bb = idx >> 3, seg = idx & 7;
    const size_t g = (size_t)(bb * 512 + s) * 2304 + h * 192 + seg * 8;
    *(uint4*)&Qs[bb * 72 + seg * 8] = *(const uint4*)&QKV[g];
    *(uint4*)&Ks[bb * 72 + seg * 8] = *(const uint4*)&QKV[g + 64];
  }
  __syncthreads();

  // ---- QK^T: wave w -> score rows [w*32, w*32+32) x 128 cols
  f32x4_t sc[2][8];
#pragma unroll
  for (int im = 0; im < 2; ++im)
#pragma unroll
    for (int in = 0; in < 8; ++in) { f32x4_t z = {0.f, 0.f, 0.f, 0.f}; sc[im][in] = z; }

#pragma unroll
  for (int kk = 0; kk < 2; ++kk) {
    bf16x8_t a0 = *(const bf16x8_t*)&Qs[(wave * 32 + lane15) * 72 + kk * 32 + quad * 8];
    bf16x8_t a1 = *(const bf16x8_t*)&Qs[(wave * 32 + 16 + lane15) * 72 + kk * 32 + quad * 8];
#pragma unroll
    for (int in = 0; in < 8; ++in) {
      bf16x8_t b = *(const bf16x8_t*)&Ks[(in * 16 + lane15) * 72 + kk * 32 + quad * 8];
      sc[0][in] = __builtin_amdgcn_mfma_f32_16x16x32_bf16(a0, b, sc[0][in], 0, 0, 0);
      sc[1][in] = __builtin_amdgcn_mfma_f32_16x16x32_bf16(a1, b, sc[1][in], 0, 0, 0);
    }
  }
  __syncthreads();  // all Qs/Ks LDS reads complete -> regions reusable

  // ---- stage V transposed into Ks region; P will go into Qs region
  unsigned short* Vt = Ks;                    // [dh][c], stride 136
  unsigned short* Ps = Qs;                    // per-wave 16x136
  {
    const int c = tid & 127, half = tid >> 7;
    const size_t vb = (size_t)(c * 512 + s) * 2304 + h * 192 + 128;
#pragma unroll
    for (int dd = 0; dd < 4; ++dd) {
      const int dseg = half * 4 + dd;
      uint4 v = *(const uint4*)&QKV[vb + dseg * 8];
      const unsigned short* pv = (const unsigned short*)&v;
#pragma unroll
      for (int j = 0; j < 8; ++j) Vt[(dseg * 8 + j) * 136 + c] = pv[j];
    }
  }

  unsigned short* myP = Ps + wave * 16 * 136;

#pragma unroll 1
  for (int im = 0; im < 2; ++im) {
#pragma unroll
    for (int r = 0; r < 4; ++r) {
      const int row = wave * 32 + im * 16 + quad * 4 + r;
      float vals[8];
      float mx = -3.0e38f;
#pragma unroll
      for (int in = 0; in < 8; ++in) {
        const int col = in * 16 + lane15;
        float v = sc[im][in][r] * 0.125f;          // /sqrt(64)
        v = (col <= row) ? -10000.0f : v;          // inverted-causal mask
        vals[in] = v;
        mx = fmaxf(mx, v);
      }
      mx = fmaxf(mx, __shfl_xor(mx, 1, 16));
      mx = fmaxf(mx, __shfl_xor(mx, 2, 16));
      mx = fmaxf(mx, __shfl_xor(mx, 4, 16));
      mx = fmaxf(mx, __shfl_xor(mx, 8, 16));
      float sum = 0.f;
#pragma unroll
      for (int in = 0; in < 8; ++in) {
        const float e_ = __expf(vals[in] - mx);
        vals[in] = e_;
        sum += e_;
      }
      sum += __shfl_xor(sum, 1, 16);
      sum += __shfl_xor(sum, 2, 16);
      sum += __shfl_xor(sum, 4, 16);
      sum += __shfl_xor(sum, 8, 16);
      const float inv = 1.0f / sum;   // row 127: uniform 1/128, exact
#pragma unroll
      for (int in = 0; in < 8; ++in)
        myP[(quad * 4 + r) * 136 + in * 16 + lane15] = f2bf(vals[in] * inv);
    }
    __syncthreads();  // covers P writes + (im==0) V staging

    // P·V: 16 rows x 64 cols, K=128
    f32x4_t oc[4];
#pragma unroll
    for (int nt = 0; nt < 4; ++nt) { f32x4_t z = {0.f, 0.f, 0.f, 0.f}; oc[nt] = z; }
#pragma unroll
    for (int kk = 0; kk < 4; ++kk) {
      bf16x8_t a = *(const bf16x8_t*)&myP[lane15 * 136 + kk * 32 + quad * 8];
#pragma unroll
      for (int nt = 0; nt < 4; ++nt) {
        bf16x8_t b = *(const bf16x8_t*)&Vt[(nt * 16 + lane15) * 136 + kk * 32 + quad * 8];
        oc[nt] = __builtin_amdgcn_mfma_f32_16x16x32_bf16(a, b, oc[nt], 0, 0, 0);
      }
    }
#pragma unroll
    for (int nt = 0; nt < 4; ++nt) {
#pragma unroll
      for (int r = 0; r < 4; ++r) {
        const int bb = wave * 32 + im * 16 + quad * 4 + r;
        Ctx[((size_t)bb * 512 + s) * 768 + h * 64 + nt * 16 + lane15] = f2bf(oc[nt][r]);
      }
    }
    __syncthreads();
  }
}

// ------------------------------------------------- GEMM2: out = ctx @ Wdense^T
__global__ __launch_bounds__(256) void gemm_out(
    const unsigned short* __restrict__ A,    // ctx bf16 [65536 x 768]
    const unsigned short* __restrict__ Bt,   // Wdb bf16 [768 x 768]
    float* __restrict__ Out) {               // fp32 [65536 x 768]
  __shared__ unsigned short As[128 * 64];
  __shared__ unsigned short Bs[128 * 64];
  const int tid = threadIdx.x;
  const int wave = tid >> 6, lane = tid & 63;
  const int lane15 = lane & 15, quad = lane >> 4;
  const int mBase = blockIdx.x * 128;
  const int nBase = blockIdx.y * 128;
  const int wm = (wave >> 1) * 64;
  const int wn = (wave & 1) * 64;

  f32x4_t acc[4][4];
#pragma unroll
  for (int i = 0; i < 4; ++i)
#pragma unroll
    for (int j = 0; j < 4; ++j) { f32x4_t z = {0.f, 0.f, 0.f, 0.f}; acc[i][j] = z; }

  const int r16 = lane & 15;
  const int ck8 = (lane >> 4) * 8;
  const unsigned short* Ag = A + (size_t)(mBase + wave * 32 + r16) * 768 + ck8;
  const unsigned short* Bg = Bt + (size_t)(nBase + wave * 32 + r16) * 768 + ck8;
  unsigned short* lA = &As[wave * 4 * 512];
  unsigned short* lB = &Bs[wave * 4 * 512];

  const int aSub = (wm >> 4) * 2;
  const int bSub = (wn >> 4) * 2;

  for (int k0 = 0; k0 < 768; k0 += 64) {
    GLL16(Ag + k0, lA);
    GLL16(Ag + k0 + 32, lA + 512);
    GLL16(Ag + 16 * 768 + k0, lA + 1024);
    GLL16(Ag + 16 * 768 + k0 + 32, lA + 1536);
    GLL16(Bg + k0, lB);
    GLL16(Bg + k0 + 32, lB + 512);
    GLL16(Bg + 16 * 768 + k0, lB + 1024);
    GLL16(Bg + 16 * 768 + k0 + 32, lB + 1536);
    __syncthreads();
#pragma unroll
    for (int kh = 0; kh < 2; ++kh) {
      bf16x8_t aF[4], bF[4];
#pragma unroll
      for (int im = 0; im < 4; ++im)
        aF[im] = *(const bf16x8_t*)&As[(aSub + im * 2 + kh) * 512 + lane * 8];
#pragma unroll
      for (int in = 0; in < 4; ++in)
        bF[in] = *(const bf16x8_t*)&Bs[(bSub + in * 2 + kh) * 512 + lane * 8];
#pragma unroll
      for (int im = 0; im < 4; ++im)
#pragma unroll
        for (int in = 0; in < 4; ++in)
          acc[im][in] = __builtin_amdgcn_mfma_f32_16x16x32_bf16(aF[im], bF[in], acc[im][in], 0, 0, 0);
    }
    __syncthreads();
  }

#pragma unroll
  for (int im = 0; im < 4; ++im) {
#pragma unroll
    for (int r = 0; r < 4; ++r) {
      const int m = mBase + wm + im * 16 + quad * 4 + r;
      float* orow = Out + (size_t)m * 768 + nBase + wn + lane15;
#pragma unroll
      for (int in = 0; in < 4; ++in)
        orow[in * 16] = acc[im][in][r];
    }
  }
}

// ---------------------------------------------------------------------- launch
extern "C" void kernel_launch(void* const* d_in, const int* in_sizes, int n_in,
                              void* d_out, int out_size, void* d_ws, size_t ws_size,
                              hipStream_t stream) {
  const float* X    = (const float*)d_in[0];   // [128,512,768]
  const float* Wqkv = (const float*)d_in[1];   // [2304,768]
  const float* bqkv = (const float*)d_in[2];   // [2304]
  const float* Wd   = (const float*)d_in[3];   // [768,768]
  const float* bd   = (const float*)d_in[4];   // [768]
  float* out = (float*)d_out;

  char* ws = (char*)d_ws;
  unsigned short* Xb  = (unsigned short*)(ws);                // 100,663,296 B (later: ctx)
  unsigned short* QKV = (unsigned short*)(ws + 100663296);    // [65536,2304] bf16
  unsigned short* Wqb = (unsigned short*)(ws + 402653184);
  unsigned short* Wdb = (unsigned short*)(ws + 406192128);

  cvt_kernel<<<dim3(49152), 256, 0, stream>>>(X, Xb, 12582912);
  cvt_kernel<<<dim3(1728), 256, 0, stream>>>(Wqkv, Wqb, 442368);
  cvt_kernel<<<dim3(576), 256, 0, stream>>>(Wd, Wdb, 147456);
  bias_tail<<<dim3(3), 256, 0, stream>>>(bd, out);

  gemm_qkv<<<dim3(512, 18), 256, 0, stream>>>(Xb, Wqb, bqkv, QKV);
  attn_kernel<<<dim3(6144), 256, 0, stream>>>(QKV, Xb /* ctx reuse */);
  gemm_out<<<dim3(512, 6), 256, 0, stream>>>(Xb, Wdb, out);
}